// Round 4
// baseline (58.657 us; speedup 1.0000x reference)
//
#include <hip/hip_runtime.h>
#include <stdint.h>

typedef __fp16 half2v __attribute__((ext_vector_type(2)));

#define KSZ    5
#define NBATCH 16
#define NC     3
#define NH     256
#define NW     256
#define TW     16
#define TH     16
#define NTAP   25
#define NPAIR  45            // 3 ch * 5 rows * 3 pairs
#define WLD    32            // padded filter dim of packed weight table
#define TROWS  20            // tile rows incl halo
#define TWRD   12            // u32 words per row (24 f16 cols)
#define CPLANE (TROWS * TWRD)  // 240 words per channel
#define COPYW  (NC * CPLANE)   // 720 words per copy

__device__ __forceinline__ uint32_t pack_f16x2(float lo, float hi) {
    half2v h = __builtin_amdgcn_cvt_pkrtz(lo, hi);
    return __builtin_bit_cast(uint32_t, h);
}

__device__ __forceinline__ float fdot2(uint32_t w, uint32_t v, float acc) {
#if __has_builtin(__builtin_amdgcn_fdot2)
    return __builtin_amdgcn_fdot2(__builtin_bit_cast(half2v, w),
                                  __builtin_bit_cast(half2v, v), acc, false);
#else
    half2v a = __builtin_bit_cast(half2v, w);
    half2v b = __builtin_bit_cast(half2v, v);
    return acc + (float)a.x * (float)b.x + (float)a.y * (float)b.y;
#endif
}

// w2T[p][k] = pack(cw[k][tap 2q of (c,i)], cw[k][tap 2q+1]) ; p = c*15+i*3+q
__global__ void prep_weights(const float* __restrict__ cw,
                             uint32_t* __restrict__ w2T)
{
    int idx = threadIdx.x + blockIdx.x * 256;
    if (idx >= NPAIR * WLD) return;
    int p = idx / WLD, k = idx - p * WLD;
    int c = p / 15, rem = p - c * 15, i = rem / 3, q = rem - i * 3;
    float lo = 0.0f, hi = 0.0f;
    if (k < NTAP) {
        const float* base = cw + k * 75 + c * 25 + i * 5;
        lo = base[2 * q];
        if (2 * q + 1 < KSZ) hi = base[2 * q + 1];
    }
    w2T[idx] = pack_f16x2(lo, hi);
}

__global__ __launch_bounds__(256, 4)
void highorder3(const float* __restrict__ x,
                const uint32_t* __restrict__ w2T,
                const float* __restrict__ cb,
                float* __restrict__ out)
{
    __shared__ uint32_t lds[2 * COPYW];   // 5760 B: copyA then copyB (shift-1)

    const int tid = threadIdx.x;
    const int bx  = blockIdx.x & 15;
    const int by  = (blockIdx.x >> 4) & 15;
    const int b   = blockIdx.x >> 8;
    const int bw0 = bx * TW;
    const int bh0 = by * TH;

    const float* xb = x + (size_t)b * NC * NH * NW;

    // Stage: word m of row r covers cols (bw0+2m-2, 2m-1) in A, (2m-1, 2m) in B
    #pragma unroll
    for (int it = 0; it < 3; ++it) {
        int idx = tid + it * 256;
        if (idx < COPYW) {
            int c   = idx / CPLANE;
            int rem = idx - c * CPLANE;
            int r   = rem / TWRD;
            int m   = rem - r * TWRD;
            int gh  = bh0 + r - 2;
            int g0  = bw0 + 2 * m - 2;
            bool rowok = (unsigned)gh < NH;
            const float* row = xb + c * NH * NW + gh * NW;
            float a0 = (rowok && (unsigned)(g0)     < NW) ? row[g0]     : 0.0f;
            float a1 = (rowok && (unsigned)(g0 + 1) < NW) ? row[g0 + 1] : 0.0f;
            float a2 = (rowok && (unsigned)(g0 + 2) < NW) ? row[g0 + 2] : 0.0f;
            lds[idx]         = pack_f16x2(a0, a1);
            lds[COPYW + idx] = pack_f16x2(a1, a2);
        }
    }
    __syncthreads();

    const int px = tid & (TW - 1);
    const int py = tid >> 4;

    // Each lane reads aligned f16x2 pairs: even px from copyA, odd from copyB.
    const uint32_t* basep = lds + ((px & 1) ? COPYW : 0) + (px >> 1);

    // Load all 45 neighborhood pairs ONCE; reused in both phases.
    uint32_t nb[NPAIR];
    #pragma unroll
    for (int c = 0; c < NC; ++c)
        #pragma unroll
        for (int i = 0; i < KSZ; ++i)
            #pragma unroll
            for (int q = 0; q < 3; ++q)
                nb[c * 15 + i * 3 + q] =
                    basep[c * CPLANE + (py + i) * TWRD + q];

    // Phase 1: acc[k] += dot2(w2T[p][k], nb[p]) ; weights wave-uniform (s_load)
    float acc[NTAP];
    #pragma unroll
    for (int k = 0; k < NTAP; ++k) acc[k] = cb[k];

    #pragma unroll
    for (int p = 0; p < NPAIR; ++p) {
        uint32_t v = nb[p];
        const uint32_t* wr = w2T + p * WLD;
        #pragma unroll
        for (int k = 0; k < NTAP; ++k)
            acc[k] = fdot2(wr[k], v, acc[k]);
    }

    // Phase 2: pack per-pixel weights into pairs, dot2 against the same nb.
    uint32_t wp[15];
    #pragma unroll
    for (int i = 0; i < KSZ; ++i) {
        wp[i * 3 + 0] = pack_f16x2(acc[i * 5 + 0], acc[i * 5 + 1]);
        wp[i * 3 + 1] = pack_f16x2(acc[i * 5 + 2], acc[i * 5 + 3]);
        wp[i * 3 + 2] = pack_f16x2(acc[i * 5 + 4], 0.0f);
    }

    float* ob = out + (size_t)b * NC * NH * NW
                    + (size_t)(bh0 + py) * NW + (bw0 + px);
    #pragma unroll
    for (int c = 0; c < NC; ++c) {
        // residual: center tap (i=2,j=2) = low half of pair (i=2,q=1)
        half2v ctr = __builtin_bit_cast(half2v, nb[c * 15 + 2 * 3 + 1]);
        float s = (float)ctr.x;
        #pragma unroll
        for (int t = 0; t < 15; ++t)
            s = fdot2(wp[t], nb[c * 15 + t], s);
        ob[(size_t)c * NH * NW] = s;
    }
}

extern "C" void kernel_launch(void* const* d_in, const int* in_sizes, int n_in,
                              void* d_out, int out_size, void* d_ws, size_t ws_size,
                              hipStream_t stream)
{
    const float* x  = (const float*)d_in[0];
    const float* cw = (const float*)d_in[1];
    const float* cb = (const float*)d_in[2];
    float* out      = (float*)d_out;
    uint32_t* w2T   = (uint32_t*)d_ws;   // 45*32*4 = 5760 B

    prep_weights<<<(NPAIR * WLD + 255) / 256, 256, 0, stream>>>(cw, w2T);

    dim3 grid(NBATCH * (NH / TH) * (NW / TW));   // 4096 blocks
    highorder3<<<grid, 256, 0, stream>>>(x, w2T, cb, out);
}

// Round 5
// 33.339 us; speedup vs baseline: 1.7594x; 1.7594x over previous
//
#include <hip/hip_runtime.h>
#include <stdint.h>

typedef __fp16    half2v __attribute__((ext_vector_type(2)));
typedef _Float16  f16x8  __attribute__((ext_vector_type(8)));
typedef float     f32x4  __attribute__((ext_vector_type(4)));
typedef uint32_t  u32x4  __attribute__((ext_vector_type(4)));

#define KSZ    5
#define NBATCH 16
#define NC     3
#define NH     256
#define NW     256
#define TW     16
#define TH     16
#define NTAP   25
#define TROWS  20
#define TWRD   12              // u32 words per tile row (24 f16 cols)
#define CPLANE (TROWS * TWRD)  // 240
#define COPYW  (NC * CPLANE)   // 720
#define WBS    257             // wbuf pixel stride (f32)

__device__ __forceinline__ uint32_t pack_f16x2(float lo, float hi) {
    half2v h = __builtin_amdgcn_cvt_pkrtz(lo, hi);
    return __builtin_bit_cast(uint32_t, h);
}

__device__ __forceinline__ float fdot2(uint32_t w, uint32_t v, float acc) {
#if __has_builtin(__builtin_amdgcn_fdot2)
    return __builtin_amdgcn_fdot2(__builtin_bit_cast(half2v, w),
                                  __builtin_bit_cast(half2v, v), acc, false);
#else
    half2v a = __builtin_bit_cast(half2v, w);
    half2v b = __builtin_bit_cast(half2v, v);
    return acc + (float)a.x * (float)b.x + (float)a.y * (float)b.y;
#endif
}

// B-fragment table for mfma_f32_16x16x32_f16.
// Element layout per lane (f = lane&15 = filter col, s = lane>>4):
//   k = s*8 + e, dword d holds elements 2d,2d+1 -> k-in-block = 2*(4s+d)(+1).
// K layout per channel block of 32: pair P = i*3+q -> taps (i, 2q),(i, 2q+1),
// pads (P>=15, j>=5, filter>=25) are ZERO.
// Flat: Bpack[(((nt*3+c)*4 + s)*16 + f)*4 + d]
__global__ void prep_B(const float* __restrict__ cw, uint32_t* __restrict__ Bpack)
{
    int idx = threadIdx.x + blockIdx.x * 256;
    if (idx >= 1536) return;
    int d  = idx & 3;
    int u4 = idx >> 2;
    int f  = u4 & 15;
    int t2 = u4 >> 4;
    int s  = t2 & 3;
    int t3 = t2 >> 2;       // 0..5
    int c  = t3 % 3;
    int nt = t3 / 3;
    int k  = nt * 16 + f;
    int P  = 4 * s + d;
    float lo = 0.0f, hi = 0.0f;
    if (k < NTAP && P < 15) {
        int i = P / 3, q = P - 3 * i;
        const float* base = cw + k * 75 + c * 25 + i * 5;
        lo = base[2 * q];
        if (2 * q + 1 < KSZ) hi = base[2 * q + 1];
    }
    Bpack[idx] = pack_f16x2(lo, hi);
}

__global__ __launch_bounds__(256, 4)
void highorder4(const float* __restrict__ x,
                const uint32_t* __restrict__ Bpack,
                const float* __restrict__ cb,
                float* __restrict__ out)
{
    __shared__ uint32_t lds_t[2 * COPYW];     // 5760 B dual-copy paired tile
    __shared__ float    wbuf[NTAP * WBS];     // 25700 B  [filter][pixel]

    const int tid = threadIdx.x;
    const int l   = tid & 63;
    const int w   = tid >> 6;
    const int fl  = l & 15;
    const int s   = l >> 4;

    const int bx  = blockIdx.x & 15;
    const int by  = (blockIdx.x >> 4) & 15;
    const int b   = blockIdx.x >> 8;
    const int bw0 = bx * TW;
    const int bh0 = by * TH;

    const float* xb = x + (size_t)b * NC * NH * NW;

    // B-fragments: 6 x 16B per lane, issued first (latency hides under staging)
    u32x4 bfr[6];
    const u32x4* Bp4 = (const u32x4*)Bpack;
    #pragma unroll
    for (int t3 = 0; t3 < 6; ++t3)
        bfr[t3] = Bp4[(t3 * 4 + s) * 16 + fl];

    // Stage dual-copy f16-pair tile (r4-verified)
    #pragma unroll
    for (int it = 0; it < 3; ++it) {
        int idx = tid + it * 256;
        if (idx < COPYW) {
            int c   = idx / CPLANE;
            int rem = idx - c * CPLANE;
            int r   = rem / TWRD;
            int m   = rem - r * TWRD;
            int gh  = bh0 + r - 2;
            int g0  = bw0 + 2 * m - 2;
            bool rowok = (unsigned)gh < NH;
            const float* row = xb + c * NH * NW + gh * NW;
            float a0 = (rowok && (unsigned)(g0)     < NW) ? row[g0]     : 0.0f;
            float a1 = (rowok && (unsigned)(g0 + 1) < NW) ? row[g0 + 1] : 0.0f;
            float a2 = (rowok && (unsigned)(g0 + 2) < NW) ? row[g0 + 2] : 0.0f;
            lds_t[idx]         = pack_f16x2(a0, a1);
            lds_t[COPYW + idx] = pack_f16x2(a1, a2);
        }
    }
    __syncthreads();

    // ---- Phase 1 as MFMA: wgt[px][flt] = sum_k A[px][k] * B[k][flt] + bias
    const float cb0 = cb[fl];
    const float cb1 = (fl < 9) ? cb[16 + fl] : 0.0f;

    f32x4 acc[4][2];
    #pragma unroll
    for (int m = 0; m < 4; ++m) {
        acc[m][0] = f32x4{cb0, cb0, cb0, cb0};
        acc[m][1] = f32x4{cb1, cb1, cb1, cb1};
    }

    // per-lane k-slice -> (tile-row, pair-col) offsets; P=15 clamps to in-range
    // dummy (i=4,q=3) whose product is annihilated by B zero-pad.
    int roff[4];
    #pragma unroll
    for (int d = 0; d < 4; ++d) {
        int P = 4 * s + d;
        int i = (P * 11) >> 5;  if (i > 4) i = 4;
        int q = P - 3 * i;
        roff[d] = i * TWRD + q;
    }

    const int abase = ((l & 1) ? COPYW : 0) + (fl >> 1);
    #pragma unroll
    for (int m = 0; m < 4; ++m) {
        const int tb = abase + (w * 4 + m) * TWRD;
        #pragma unroll
        for (int c = 0; c < NC; ++c) {
            u32x4 av;
            #pragma unroll
            for (int d = 0; d < 4; ++d)
                av[d] = lds_t[tb + c * CPLANE + roff[d]];
            f16x8 A = __builtin_bit_cast(f16x8, av);
            acc[m][0] = __builtin_amdgcn_mfma_f32_16x16x32_f16(
                A, __builtin_bit_cast(f16x8, bfr[c]),     acc[m][0], 0, 0, 0);
            acc[m][1] = __builtin_amdgcn_mfma_f32_16x16x32_f16(
                A, __builtin_bit_cast(f16x8, bfr[3 + c]), acc[m][1], 0, 0, 0);
        }
    }

    // D layout: col = lane&15 = filter, row = s*4 + reg = px. Write transposed.
    #pragma unroll
    for (int m = 0; m < 4; ++m) {
        #pragma unroll
        for (int nt = 0; nt < 2; ++nt) {
            int flt = nt * 16 + fl;
            if (flt < NTAP) {
                int pbase = (w * 4 + m) * 16 + s * 4;
                #pragma unroll
                for (int r = 0; r < 4; ++r)
                    wbuf[flt * WBS + pbase + r] = acc[m][nt][r];
            }
        }
    }
    __syncthreads();

    // ---- Phase 2: per-pixel dynamic aggregation + residual (r4-verified)
    const int px = tid & 15;
    const int py = tid >> 4;
    const uint32_t* basep = lds_t + ((px & 1) ? COPYW : 0) + (px >> 1);

    uint32_t nb[45];
    #pragma unroll
    for (int c = 0; c < NC; ++c)
        #pragma unroll
        for (int i = 0; i < KSZ; ++i)
            #pragma unroll
            for (int q = 0; q < 3; ++q)
                nb[c * 15 + i * 3 + q] =
                    basep[c * CPLANE + (py + i) * TWRD + q];

    float wg[NTAP];
    #pragma unroll
    for (int k = 0; k < NTAP; ++k)
        wg[k] = wbuf[k * WBS + tid];

    uint32_t wp[15];
    #pragma unroll
    for (int i = 0; i < KSZ; ++i) {
        wp[i * 3 + 0] = pack_f16x2(wg[i * 5 + 0], wg[i * 5 + 1]);
        wp[i * 3 + 1] = pack_f16x2(wg[i * 5 + 2], wg[i * 5 + 3]);
        wp[i * 3 + 2] = pack_f16x2(wg[i * 5 + 4], 0.0f);
    }

    float* ob = out + (size_t)b * NC * NH * NW
                    + (size_t)(bh0 + py) * NW + (bw0 + px);
    #pragma unroll
    for (int c = 0; c < NC; ++c) {
        half2v ctr = __builtin_bit_cast(half2v, nb[c * 15 + 2 * 3 + 1]);
        float sum = (float)ctr.x;
        #pragma unroll
        for (int t = 0; t < 15; ++t)
            sum = fdot2(wp[t], nb[c * 15 + t], sum);
        ob[(size_t)c * NH * NW] = sum;
    }
}

extern "C" void kernel_launch(void* const* d_in, const int* in_sizes, int n_in,
                              void* d_out, int out_size, void* d_ws, size_t ws_size,
                              hipStream_t stream)
{
    const float* x  = (const float*)d_in[0];
    const float* cw = (const float*)d_in[1];
    const float* cb = (const float*)d_in[2];
    float* out      = (float*)d_out;
    uint32_t* Bpack = (uint32_t*)d_ws;   // 1536 * 4 = 6144 B

    prep_B<<<6, 256, 0, stream>>>(cw, Bpack);

    dim3 grid(NBATCH * (NH / TH) * (NW / TW));   // 4096 blocks
    highorder4<<<grid, 256, 0, stream>>>(x, Bpack, cb, out);
}

// Round 7
// 29.402 us; speedup vs baseline: 1.9950x; 1.1339x over previous
//
#include <hip/hip_runtime.h>
#include <stdint.h>

typedef __fp16    half2v __attribute__((ext_vector_type(2)));
typedef _Float16  f16x8  __attribute__((ext_vector_type(8)));
typedef float     f32x4  __attribute__((ext_vector_type(4)));
typedef uint32_t  u32x4  __attribute__((ext_vector_type(4)));

#define KSZ    5
#define NBATCH 16
#define NC     3
#define NH     256
#define NW     256
#define TW     16
#define TH     16
#define NTAP   25
#define TROWS  20
#define TWRD   12               // u32 words per tile row (24 f16 cols)
#define CPLANE (TROWS * TWRD)   // 240
#define COPYW  (NC * CPLANE)    // 720
#define PBS    17               // pbuf px stride (conflict pad)

__device__ __forceinline__ uint32_t pack_f16x2(float lo, float hi) {
    half2v h = __builtin_amdgcn_cvt_pkrtz(lo, hi);
    return __builtin_bit_cast(uint32_t, h);
}

__device__ __forceinline__ float fdot2(uint32_t w, uint32_t v, float acc) {
#if __has_builtin(__builtin_amdgcn_fdot2)
    return __builtin_amdgcn_fdot2(__builtin_bit_cast(half2v, w),
                                  __builtin_bit_cast(half2v, v), acc, false);
#else
    half2v a = __builtin_bit_cast(half2v, w);
    half2v b = __builtin_bit_cast(half2v, v);
    return acc + (float)a.x * (float)b.x + (float)a.y * (float)b.y;
#endif
}

// SHARED slot->pair map: k-slot (s, dword d) holds tap-pair P, halves = taps
// (i, 2q), (i, 2q+1) with P = i*3+q. Used by BOTH prep and main kernel.
__device__ __forceinline__ int pair_of(int s, int d) {
    return (d < 2) ? (2 * s + d) : (8 + 2 * s + (d - 2));
}

// Virtual filters: vf = i*6 + jj; jj<5 -> real filter f = i*5+jj; jj==5 or
// vf>=30 -> zero pad row. Atab flat idx = t3*256 + s*64 + fl*4 + d,
// t3 = mt*3 + c, vf = mt*16 + fl. cbv[vf] = bias or 0.
__global__ void prep_AB(const float* __restrict__ cw, const float* __restrict__ cb,
                        uint32_t* __restrict__ Atab, float* __restrict__ cbv)
{
    int idx = threadIdx.x + blockIdx.x * 256;
    if (idx < 1536) {
        int d  = idx & 3;
        int fl = (idx >> 2) & 15;
        int s  = (idx >> 6) & 3;
        int t3 = idx >> 8;            // 0..5
        int c  = t3 % 3, mt = t3 / 3;
        int vf = mt * 16 + fl;
        int P  = pair_of(s, d);
        float lo = 0.0f, hi = 0.0f;
        if (vf < 30 && (vf % 6) != 5 && P < 15) {
            int f = (vf / 6) * 5 + (vf % 6);
            int i = P / 3, q = P - 3 * i;
            const float* base = cw + f * 75 + c * 25 + i * 5;
            lo = base[2 * q];
            if (q < 2) hi = base[2 * q + 1];
        }
        Atab[idx] = pack_f16x2(lo, hi);
    } else if (idx < 1568) {
        int vf = idx - 1536;
        float v = 0.0f;
        if (vf < 30 && (vf % 6) != 5) v = cb[(vf / 6) * 5 + (vf % 6)];
        cbv[vf] = v;
    }
}

__global__ __launch_bounds__(256, 2)
void highorder6(const float* __restrict__ x,
                const uint32_t* __restrict__ Atab,
                const float* __restrict__ cbv,
                float* __restrict__ out)
{
    __shared__ uint32_t lds_t[2 * COPYW];       // 5760 B dual-copy f16-pair tile
    __shared__ uint32_t pbuf[TH * 16 * PBS];    // 17408 B: [py][pair t][px]

    const int tid = threadIdx.x;
    const int l   = tid & 63;
    const int w   = tid >> 6;
    const int fl  = l & 15;     // A row (vf) and D col (px) index
    const int s   = l >> 4;     // k-slice / D row group

    const int bx  = blockIdx.x & 15;
    const int by  = (blockIdx.x >> 4) & 15;
    const int b   = blockIdx.x >> 8;
    const int bw0 = bx * TW;
    const int bh0 = by * TH;

    const float* xb = x + (size_t)b * NC * NH * NW;

    // A-fragments (weights) + bias
    u32x4 afr[6];
    const u32x4* At4 = (const u32x4*)Atab;
    #pragma unroll
    for (int t3 = 0; t3 < 6; ++t3)
        afr[t3] = At4[(t3 * 4 + s) * 16 + fl];
    const f32x4* cbv4 = (const f32x4*)cbv;
    const f32x4 cbA = cbv4[s];       // rows vf = 4s+r
    const f32x4 cbB = cbv4[4 + s];   // rows vf = 16+4s+r

    // Stage dual-copy f16-pair tile (r5-verified verbatim)
    #pragma unroll
    for (int it = 0; it < 3; ++it) {
        int idx = tid + it * 256;
        if (idx < COPYW) {
            int c   = idx / CPLANE;
            int rem = idx - c * CPLANE;
            int r   = rem / TWRD;
            int m   = rem - r * TWRD;
            int gh  = bh0 + r - 2;
            int g0  = bw0 + 2 * m - 2;
            bool rowok = (unsigned)gh < NH;
            const float* row = xb + c * NH * NW + gh * NW;
            float a0 = (rowok && (unsigned)(g0)     < NW) ? row[g0]     : 0.0f;
            float a1 = (rowok && (unsigned)(g0 + 1) < NW) ? row[g0 + 1] : 0.0f;
            float a2 = (rowok && (unsigned)(g0 + 2) < NW) ? row[g0 + 2] : 0.0f;
            lds_t[idx]         = pack_f16x2(a0, a1);
            lds_t[COPYW + idx] = pack_f16x2(a1, a2);
        }
    }
    __syncthreads();

    // per-lane word offsets for pairs pair_of(s,d); P==15 -> clamp (A is zero)
    int woff[4];
    #pragma unroll
    for (int d = 0; d < 4; ++d) {
        int P = pair_of(s, d);
        int i = P / 3, q = P - 3 * i;
        woff[d] = (P == 15) ? 0 : (i * TWRD + q);
    }
    const int abase = ((fl & 1) ? COPYW : 0) + (fl >> 1);

    #pragma unroll
    for (int g = 0; g < 4; ++g) {
        const int py = w * 4 + g;
        const int bg = abase + py * TWRD;

        u32x4 bv[3];
        #pragma unroll
        for (int c = 0; c < 3; ++c)
            #pragma unroll
            for (int d = 0; d < 4; ++d)
                bv[c][d] = lds_t[bg + c * CPLANE + woff[d]];

        // Phase 1: wgt[vf][px] = conv + bias, 2 M-tiles x 3 K-steps
        f32x4 a0 = cbA, a1 = cbB;
        #pragma unroll
        for (int c = 0; c < 3; ++c) {
            f16x8 B = __builtin_bit_cast(f16x8, bv[c]);
            a0 = __builtin_amdgcn_mfma_f32_16x16x32_f16(
                     __builtin_bit_cast(f16x8, afr[c]),     B, a0, 0, 0, 0);
            a1 = __builtin_amdgcn_mfma_f32_16x16x32_f16(
                     __builtin_bit_cast(f16x8, afr[3 + c]), B, a1, 0, 0, 0);
        }

        // In-lane: rows (4s+r) pack to weight-pairs t = 2s,2s+1,8+2s,9+2s
        uint32_t wq0 = pack_f16x2(a0[0], a0[1]);
        uint32_t wq1 = pack_f16x2(a0[2], a0[3]);
        uint32_t wq2 = pack_f16x2(a1[0], a1[1]);
        uint32_t wq3 = pack_f16x2(a1[2], a1[3]);

        pbuf[(py * 16 + (2 * s))     * PBS + fl] = wq0;
        pbuf[(py * 16 + (2 * s + 1)) * PBS + fl] = wq1;
        pbuf[(py * 16 + (8 + 2 * s)) * PBS + fl] = wq2;
        if (s < 3)
            pbuf[(py * 16 + (9 + 2 * s)) * PBS + fl] = wq3;  // t=15 pad skipped
    }
    __syncthreads();

    // ---- Phase 2: r4-VERIFIED path (nb re-read + fdot2 + residual)
    const int px  = tid & 15;
    const int py2 = tid >> 4;
    const uint32_t* basep = lds_t + ((px & 1) ? COPYW : 0) + (px >> 1);

    uint32_t nb[45];
    #pragma unroll
    for (int c = 0; c < NC; ++c)
        #pragma unroll
        for (int i = 0; i < KSZ; ++i)
            #pragma unroll
            for (int q = 0; q < 3; ++q)
                nb[c * 15 + i * 3 + q] =
                    basep[c * CPLANE + (py2 + i) * TWRD + q];

    uint32_t wp[15];
    #pragma unroll
    for (int t = 0; t < 15; ++t)
        wp[t] = pbuf[(py2 * 16 + t) * PBS + px];

    float* ob = out + (size_t)b * NC * NH * NW
                    + (size_t)(bh0 + py2) * NW + (bw0 + px);
    #pragma unroll
    for (int c = 0; c < NC; ++c) {
        // residual: center tap (i=2,j=2) = lo half of pair (i=2,q=1) -> idx 7
        half2v ctr = __builtin_bit_cast(half2v, nb[c * 15 + 7]);
        float sum = (float)ctr.x;
        #pragma unroll
        for (int t = 0; t < 15; ++t)
            sum = fdot2(wp[t], nb[c * 15 + t], sum);
        ob[(size_t)c * NH * NW] = sum;
    }
}

extern "C" void kernel_launch(void* const* d_in, const int* in_sizes, int n_in,
                              void* d_out, int out_size, void* d_ws, size_t ws_size,
                              hipStream_t stream)
{
    const float* x  = (const float*)d_in[0];
    const float* cw = (const float*)d_in[1];
    const float* cb = (const float*)d_in[2];
    float* out      = (float*)d_out;
    uint32_t* Atab  = (uint32_t*)d_ws;                    // 6144 B
    float*    cbv   = (float*)((char*)d_ws + 6144);       // 128 B

    prep_AB<<<7, 256, 0, stream>>>(cw, cb, Atab, cbv);

    dim3 grid(NBATCH * (NH / TH) * (NW / TW));   // 4096 blocks
    highorder6<<<grid, 256, 0, stream>>>(x, Atab, cbv, out);
}